// Round 8
// baseline (178.277 us; speedup 1.0000x reference)
//
#include <hip/hip_runtime.h>
#include <hip/hip_bf16.h>
#include <cstdint>

#define HW 128
#define MASK_ELEMS (HW * HW)
#define SBLK 1024      // sampler block size (16 waves)
#define NBLK 256       // sampler grid size (1 block/CU via 128KB LDS)

typedef unsigned short ushort_t;
typedef __attribute__((ext_vector_type(4))) unsigned short ushort4_t;
typedef __attribute__((ext_vector_type(8))) short short8;
typedef __attribute__((ext_vector_type(4))) float f32x4;

__device__ __forceinline__ float asf(unsigned int u) {
    union { unsigned int i; float f; } c;
    c.i = u;
    return c.f;
}
__device__ __forceinline__ ushort_t f2bf(float f) {
    union { float f; unsigned int i; } c;
    c.f = f;
    unsigned int r = c.i + 0x7FFFu + ((c.i >> 16) & 1u);  // RNE
    return (ushort_t)(r >> 16);
}

// LDS-visibility-only barrier: NO vmcnt drain (keeps stage loads/stores in flight).
#define LDS_BARRIER()                                         \
    do {                                                      \
        asm volatile("s_waitcnt lgkmcnt(0)" ::: "memory");    \
        __builtin_amdgcn_s_barrier();                         \
    } while (0)

// ---------- kernel 1: per-point bilinear setup -> base idx + 4 packed bf16 weight products ----
// Base b clamped so bx<=126, by<=126: taps {b, b+1, b+128, b+129} all in [0,16384).
__global__ void kprep(const float* __restrict__ coords, int* __restrict__ idx,
                      uint2* __restrict__ wpk, int P) {
    int i = blockIdx.x * 256 + threadIdx.x;
    if (i >= P) return;
    float cx = coords[2 * i], cy = coords[2 * i + 1];
    float x = cx * (float)HW - 0.5f;
    float y = cy * (float)HW - 0.5f;
    float x0f = floorf(x), y0f = floorf(y);
    float wx1 = x - x0f, wy1 = y - y0f;
    float wx0 = 1.f - wx1, wy0 = 1.f - wy1;
    int x0 = (int)x0f, y0 = (int)y0f;

    float wxA = (x0 >= 0) ? wx0 : wx1;
    float wxB = (x0 >= 0 && x0 < HW - 1) ? wx1 : 0.f;
    float wyA = (y0 >= 0) ? wy0 : wy1;
    float wyB = (y0 >= 0 && y0 < HW - 1) ? wy1 : 0.f;
    int bx = max(x0, 0), by = max(y0, 0);
    if (bx > HW - 2) { bx = HW - 2; wxB = wxA; wxA = 0.f; }
    if (by > HW - 2) { by = HW - 2; wyB = wyA; wyA = 0.f; }

    idx[i] = by * HW + bx;
    wpk[i] = make_uint2((unsigned)f2bf(wxA * wyA) | ((unsigned)f2bf(wxB * wyA) << 16),
                        (unsigned)f2bf(wxA * wyB) | ((unsigned)f2bf(wxB * wyB) << 16));
}

// ---------- kernel 2: persistent fused sampler, reg-staged 3-deep pipeline ----------
// While sampling mask k (LDS), regs hold mask k+1 (to ds_write next) and mask k+2 (loads in
// flight). Barriers are lgkmcnt-only: vmem is NEVER drained at a barrier — plain float4
// stage loads ride the proven 6.3TB/s path with a >=1-iteration landing window (T14).
__global__ __launch_bounds__(SBLK) void ksamp_all(
        const float* __restrict__ pmask, const float* __restrict__ tmasks,
        const int* __restrict__ idx, const uint2* __restrict__ wpk,
        ushort_t* __restrict__ S, ushort_t* __restrict__ tsamp,
        float* __restrict__ ssum, float* __restrict__ tsum,
        const int* __restrict__ lvl, int N, int T, int P) {
    if (*lvl >= 2) return;
    __shared__ float buf[2][MASK_ELEMS];     // 128 KB double buffer
    __shared__ float wred[2][SBLK / 64];
    const int tid = threadIdx.x;
    const int NM = N + T;
    const int nq = P >> 2;

    // ---- mask-invariant point metadata in registers ----
    int4 idr[4];
    uint4 war[4], wbr[4];
    #pragma unroll
    for (int it = 0; it < 4; ++it) {
        int q = it * SBLK + tid;
        if (q < nq) {
            idr[it] = ((const int4*)idx)[q];
            war[it] = ((const uint4*)wpk)[2 * q];
            wbr[it] = ((const uint4*)wpk)[2 * q + 1];
        } else {
            idr[it] = make_int4(0, 0, 0, 0);
            war[it] = make_uint4(0, 0, 0, 0);
            wbr[it] = make_uint4(0, 0, 0, 0);
        }
    }

    auto mptr = [&](int mi) -> const float* {
        return (mi < N) ? pmask + (size_t)mi * MASK_ELEMS
                        : tmasks + (size_t)(mi - N) * MASK_ELEMS;
    };

    const int b = blockIdx.x;
    const int rounds = (NM - b + NBLK - 1) / NBLK;   // masks this block handles
    if (rounds <= 0) return;

    float4 rA[4], rB[4];
    // prologue: mask0 -> LDS via rB; issue mask1 -> rA, mask2 -> rB
    {
        const float* g = mptr(b);
        #pragma unroll
        for (int j = 0; j < 4; ++j) rB[j] = *(const float4*)(g + j * (SBLK * 4) + tid * 4);
        #pragma unroll
        for (int j = 0; j < 4; ++j) *(float4*)&buf[0][j * (SBLK * 4) + tid * 4] = rB[j];
        if (1 < rounds) {
            const float* g1 = mptr(b + NBLK);
            #pragma unroll
            for (int j = 0; j < 4; ++j) rA[j] = *(const float4*)(g1 + j * (SBLK * 4) + tid * 4);
        }
        if (2 < rounds) {
            const float* g2 = mptr(b + 2 * NBLK);
            #pragma unroll
            for (int j = 0; j < 4; ++j) rB[j] = *(const float4*)(g2 + j * (SBLK * 4) + tid * 4);
        }
    }
    LDS_BARRIER();

    // one mask: prep next buffer from reg-set R, refill R from mask k+3, sample buf[k&1]
    #define DO_MASK(kk, R)                                                                 \
    {                                                                                      \
        const int cur = (kk) & 1;                                                          \
        const int mi = b + (kk) * NBLK;                                                    \
        if ((kk) + 1 < rounds) {                                                           \
            _Pragma("unroll")                                                              \
            for (int j = 0; j < 4; ++j)                                                    \
                *(float4*)&buf[cur ^ 1][j * (SBLK * 4) + tid * 4] = R[j];                  \
            if ((kk) + 3 < rounds) {                                                       \
                const float* gn = mptr(b + ((kk) + 3) * NBLK);                             \
                _Pragma("unroll")                                                          \
                for (int j = 0; j < 4; ++j)                                                \
                    R[j] = *(const float4*)(gn + j * (SBLK * 4) + tid * 4);                \
            }                                                                              \
        }                                                                                  \
        const float* lm = &buf[cur][0];                                                    \
        const bool sig = (mi < N);                                                         \
        ushort4_t* o4 = sig ? (ushort4_t*)(S + (size_t)mi * P)                             \
                            : (ushort4_t*)(tsamp + (size_t)(mi - N) * P);                  \
        float sum = 0.f;                                                                   \
        _Pragma("unroll")                                                                  \
        for (int it = 0; it < 4; ++it) {                                                   \
            int q = it * SBLK + tid;                                                       \
            if (q < nq) {                                                                  \
                float v[4];                                                                \
                int bi[4] = {idr[it].x, idr[it].y, idr[it].z, idr[it].w};                   \
                unsigned wa[4] = {war[it].x, war[it].z, wbr[it].x, wbr[it].z};              \
                unsigned wb[4] = {war[it].y, war[it].w, wbr[it].y, wbr[it].w};              \
                _Pragma("unroll")                                                          \
                for (int p2 = 0; p2 < 4; ++p2) {                                           \
                    int bb = bi[p2];                                                       \
                    float t00 = lm[bb], t01 = lm[bb + 1];                                  \
                    float t10 = lm[bb + HW], t11 = lm[bb + HW + 1];                        \
                    float vv = asf(wa[p2] << 16) * t00 + asf(wa[p2] & 0xffff0000u) * t01   \
                             + asf(wb[p2] << 16) * t10 + asf(wb[p2] & 0xffff0000u) * t11;  \
                    if (sig) vv = __builtin_amdgcn_rcpf(1.f + __expf(-vv));                \
                    v[p2] = vv;                                                            \
                }                                                                          \
                ushort4_t o = {f2bf(v[0]), f2bf(v[1]), f2bf(v[2]), f2bf(v[3])};            \
                o4[q] = o;                                                                 \
                sum += (v[0] + v[1]) + (v[2] + v[3]);                                      \
            }                                                                              \
        }                                                                                  \
        _Pragma("unroll")                                                                  \
        for (int m2 = 32; m2 > 0; m2 >>= 1) sum += __shfl_xor(sum, m2, 64);                \
        if ((tid & 63) == 0) wred[(kk) & 1][tid >> 6] = sum;                               \
        LDS_BARRIER();                                                                     \
        if (tid == 0) {                                                                    \
            float s = 0.f;                                                                 \
            _Pragma("unroll")                                                              \
            for (int w2 = 0; w2 < SBLK / 64; ++w2) s += wred[(kk) & 1][w2];                \
            if (sig) ssum[mi] = s;                                                         \
            else tsum[mi - N] = s;                                                         \
        }                                                                                  \
    }

    int k = 0;
    while (true) {
        DO_MASK(k, rA);             // even k: buffer-prep from rA
        ++k;
        if (k >= rounds) break;
        DO_MASK(k, rB);             // odd k: buffer-prep from rB
        ++k;
        if (k >= rounds) break;
    }
    #undef DO_MASK
}

// ---------- kernel 3: MFMA split-K GEMM: Cpart[ks][n][t] = sum_k S[n,k]*Tm[t,k] ----------
#define LDF(Aarr, Barr, kof)                                                              \
    do {                                                                                  \
        _Pragma("unroll") for (int m_ = 0; m_ < 3; ++m_)                                  \
            Aarr[m_] = *(const short8*)(pa + (size_t)m_ * 16 * P + (kof));                \
        _Pragma("unroll") for (int j_ = 0; j_ < 5; ++j_)                                  \
            Barr[j_] = *(const short8*)(pb + (size_t)j_ * 16 * P + (kof));                \
    } while (0)

#define FMAS(Aarr, Barr)                                                                  \
    do {                                                                                  \
        _Pragma("unroll") for (int m_ = 0; m_ < 3; ++m_) {                                \
            _Pragma("unroll") for (int j_ = 0; j_ < 5; ++j_)                              \
                acc[m_][j_] = __builtin_amdgcn_mfma_f32_16x16x32_bf16(                    \
                    Aarr[m_], Barr[j_], acc[m_][j_], 0, 0, 0);                            \
        }                                                                                 \
    } while (0)

__global__ __launch_bounds__(256) void kgemm(const ushort_t* __restrict__ S,
                                             const ushort_t* __restrict__ Tm,
                                             float* __restrict__ Cpart,
                                             const int* __restrict__ lvl,
                                             int N, int T, int P, int nsteps) {
    if (*lvl >= 2) return;
    int tid = threadIdx.x;
    int wid = tid >> 6, lane = tid & 63;
    int wm = wid >> 1, wt = wid & 1;
    int r = lane & 15, g = lane >> 4;
    int n0 = blockIdx.x * 96 + wm * 48;
    int t0 = wt * 80;
    size_t k0 = (size_t)blockIdx.y * nsteps * 32 + g * 8;
    const ushort_t* pa = S + (size_t)(n0 + r) * P + k0;
    const ushort_t* pb = Tm + (size_t)(t0 + r) * P + k0;

    f32x4 acc[3][5];
    #pragma unroll
    for (int m2 = 0; m2 < 3; ++m2)
        #pragma unroll
        for (int j2 = 0; j2 < 5; ++j2) acc[m2][j2] = (f32x4){0.f, 0.f, 0.f, 0.f};

    short8 a0[3], b0[5], a1[3], b1[5];
    LDF(a0, b0, 0);
    int ks = 0;
    for (; ks + 2 < nsteps; ks += 2) {
        LDF(a1, b1, (ks + 1) * 32);
        FMAS(a0, b0);
        LDF(a0, b0, (ks + 2) * 32);
        FMAS(a1, b1);
    }
    LDF(a1, b1, (ks + 1) * 32);
    FMAS(a0, b0);
    FMAS(a1, b1);

    size_t cb = (size_t)blockIdx.y * N * T;
    #pragma unroll
    for (int m2 = 0; m2 < 3; ++m2)
        #pragma unroll
        for (int j2 = 0; j2 < 5; ++j2)
            #pragma unroll
            for (int q = 0; q < 4; ++q) {
                int row = n0 + m2 * 16 + g * 4 + q;
                int col = t0 + j2 * 16 + r;
                Cpart[cb + (size_t)row * T + col] = acc[m2][j2][q];
            }
}

// ---------- kernel 4: epilogue ----------
__global__ void kfinal(const float* __restrict__ logits, const float* __restrict__ opts,
                       const float* __restrict__ tpts, const float* __restrict__ Cpart,
                       const float* __restrict__ ssum, const float* __restrict__ tsum,
                       const int* __restrict__ lvl, float* __restrict__ out,
                       int N, int T, int nks) {
    int idx = blockIdx.x * 256 + threadIdx.x;
    if (idx >= N * T) return;
    int n = idx / T, t = idx - n * T;

    float lg = logits[n];
    float p = 1.f / (1.f + __expf(-lg));
    float pos = 0.25f * (1.f - p) * (1.f - p) * (-logf(p + 1e-8f));
    float neg = 0.75f * p * p * (-logf(1.f - p + 1e-8f));
    float ccls = pos - neg;

    float kp = 0.f;
    const float4* a4 = (const float4*)(opts + (size_t)n * 32);
    const float4* b4 = (const float4*)(tpts + (size_t)t * 32);
    #pragma unroll
    for (int j = 0; j < 8; ++j) {
        float4 a = a4[j], b = b4[j];
        kp += fabsf(a.x - b.x) + fabsf(a.y - b.y) + fabsf(a.z - b.z) + fabsf(a.w - b.w);
    }

    float dice = 0.f;
    if (*lvl < 2) {
        float dot = 0.f;
        for (int ks = 0; ks < nks; ++ks) dot += Cpart[(size_t)ks * N * T + idx];
        dice = 1.f - (2.f * dot + 1.f) / (ssum[n] + tsum[t] + 1.f);
    }
    out[idx] = 2.f * ccls + 5.f * kp + 5.f * dice;
}

extern "C" void kernel_launch(void* const* d_in, const int* in_sizes, int n_in,
                              void* d_out, int out_size, void* d_ws, size_t ws_size,
                              hipStream_t stream) {
    const float* logits = (const float*)d_in[0];
    const float* cpts   = (const float*)d_in[1];
    const float* pmask  = (const float*)d_in[2];
    const float* tpts   = (const float*)d_in[3];
    const float* tmasks = (const float*)d_in[4];
    const float* coords = (const float*)d_in[5];
    const int*   lvl    = (const int*)d_in[6];
    float* out = (float*)d_out;

    int N = in_sizes[0];        // 2400
    int T = in_sizes[3] / 32;   // 160
    int P = in_sizes[5] / 2;    // 12544

    char* w = (char*)d_ws;
    auto alloc = [&](size_t bytes) {
        char* r = w;
        w += (bytes + 255) & ~(size_t)255;
        return r;
    };
    int*      idxb  = (int*)alloc((size_t)P * 4);
    uint2*    wpkb  = (uint2*)alloc((size_t)P * 8);
    ushort_t* tsamp = (ushort_t*)alloc((size_t)T * P * 2);
    ushort_t* S     = (ushort_t*)alloc((size_t)N * P * 2);
    float*    ssumb = (float*)alloc((size_t)N * 4);
    float*    tsumb = (float*)alloc((size_t)T * 4);
    size_t base_bytes = (size_t)(w - (char*)d_ws);

    int nks = 14;               // 25x14 = 350 blocks; Cpart round-trip halved vs 28
    if (base_bytes + (size_t)nks * N * T * 4 > ws_size) nks = 7;
    int nsteps = (P / 32) / nks;
    float* Cpart = (float*)alloc((size_t)nks * N * T * 4);

    kprep<<<(P + 255) / 256, 256, 0, stream>>>(coords, idxb, wpkb, P);
    ksamp_all<<<NBLK, SBLK, 0, stream>>>(pmask, tmasks, idxb, wpkb, S, tsamp,
                                         ssumb, tsumb, lvl, N, T, P);
    kgemm<<<dim3(N / 96, nks), 256, 0, stream>>>(S, tsamp, Cpart, lvl, N, T, P, nsteps);
    kfinal<<<(N * T + 255) / 256, 256, 0, stream>>>(logits, cpts, tpts, Cpart, ssumb, tsumb,
                                                    lvl, out, N, T, nks);
}

// Round 9
// 177.421 us; speedup vs baseline: 1.0048x; 1.0048x over previous
//
#include <hip/hip_runtime.h>
#include <hip/hip_bf16.h>
#include <cstdint>

#define HW 128
#define MASK_ELEMS (HW * HW)
#define SBLK 1024      // sampler block size (16 waves)
#define NBLK 256       // sampler grid size (1 block/CU via 128KB LDS)

typedef unsigned short ushort_t;
typedef __attribute__((ext_vector_type(4))) unsigned short ushort4_t;
typedef __attribute__((ext_vector_type(8))) short short8;
typedef __attribute__((ext_vector_type(4))) float f32x4;

__device__ __forceinline__ float asf(unsigned int u) {
    union { unsigned int i; float f; } c;
    c.i = u;
    return c.f;
}
__device__ __forceinline__ ushort_t f2bf(float f) {
    union { float f; unsigned int i; } c;
    c.f = f;
    unsigned int r = c.i + 0x7FFFu + ((c.i >> 16) & 1u);  // RNE
    return (ushort_t)(r >> 16);
}

// LDS-visibility-only barrier: NO vmcnt drain (keeps stage loads/stores in flight).
#define LDS_BARRIER()                                         \
    do {                                                      \
        asm volatile("s_waitcnt lgkmcnt(0)" ::: "memory");    \
        __builtin_amdgcn_s_barrier();                         \
    } while (0)

// ---------- kernel 1: per-point bilinear setup -> base idx + 4 packed bf16 weight products ----
// Base b clamped so bx<=126, by<=126: taps {b, b+1, b+128, b+129} all in [0,16384).
__global__ void kprep(const float* __restrict__ coords, int* __restrict__ idx,
                      uint2* __restrict__ wpk, int P) {
    int i = blockIdx.x * 256 + threadIdx.x;
    if (i >= P) return;
    float cx = coords[2 * i], cy = coords[2 * i + 1];
    float x = cx * (float)HW - 0.5f;
    float y = cy * (float)HW - 0.5f;
    float x0f = floorf(x), y0f = floorf(y);
    float wx1 = x - x0f, wy1 = y - y0f;
    float wx0 = 1.f - wx1, wy0 = 1.f - wy1;
    int x0 = (int)x0f, y0 = (int)y0f;

    float wxA = (x0 >= 0) ? wx0 : wx1;
    float wxB = (x0 >= 0 && x0 < HW - 1) ? wx1 : 0.f;
    float wyA = (y0 >= 0) ? wy0 : wy1;
    float wyB = (y0 >= 0 && y0 < HW - 1) ? wy1 : 0.f;
    int bx = max(x0, 0), by = max(y0, 0);
    if (bx > HW - 2) { bx = HW - 2; wxB = wxA; wxA = 0.f; }
    if (by > HW - 2) { by = HW - 2; wyB = wyA; wyA = 0.f; }

    idx[i] = by * HW + bx;
    wpk[i] = make_uint2((unsigned)f2bf(wxA * wyA) | ((unsigned)f2bf(wxB * wyA) << 16),
                        (unsigned)f2bf(wxA * wyB) | ((unsigned)f2bf(wxB * wyB) << 16));
}

// ---------- kernel 2: persistent fused sampler, reg-staged 3-deep pipeline ----------
// While sampling mask k (LDS), regs hold mask k+1 (to ds_write next) and mask k+2 (loads in
// flight). Barriers are lgkmcnt-only: vmem is NEVER drained at a barrier.
// __launch_bounds__(SBLK, 4): 4 waves/EU = 1 block/CU -> VGPR budget 128. Without the ",4"
// the compiler targets 8 waves/EU (64 VGPR) and SPILLS the 80-reg live state to scratch
// every mask (r8: VGPR=64, WRITE_SIZE 224MB vs 64MB model -> 160MB spill traffic).
__global__ __launch_bounds__(SBLK, 4) void ksamp_all(
        const float* __restrict__ pmask, const float* __restrict__ tmasks,
        const int* __restrict__ idx, const uint2* __restrict__ wpk,
        ushort_t* __restrict__ S, ushort_t* __restrict__ tsamp,
        float* __restrict__ ssum, float* __restrict__ tsum,
        const int* __restrict__ lvl, int N, int T, int P) {
    if (*lvl >= 2) return;
    __shared__ float buf[2][MASK_ELEMS];     // 128 KB double buffer
    __shared__ float wred[2][SBLK / 64];
    const int tid = threadIdx.x;
    const int NM = N + T;
    const int nq = P >> 2;

    // ---- mask-invariant point metadata in registers ----
    int4 idr[4];
    uint4 war[4], wbr[4];
    #pragma unroll
    for (int it = 0; it < 4; ++it) {
        int q = it * SBLK + tid;
        if (q < nq) {
            idr[it] = ((const int4*)idx)[q];
            war[it] = ((const uint4*)wpk)[2 * q];
            wbr[it] = ((const uint4*)wpk)[2 * q + 1];
        } else {
            idr[it] = make_int4(0, 0, 0, 0);
            war[it] = make_uint4(0, 0, 0, 0);
            wbr[it] = make_uint4(0, 0, 0, 0);
        }
    }

    auto mptr = [&](int mi) -> const float* {
        return (mi < N) ? pmask + (size_t)mi * MASK_ELEMS
                        : tmasks + (size_t)(mi - N) * MASK_ELEMS;
    };

    const int b = blockIdx.x;
    const int rounds = (NM - b + NBLK - 1) / NBLK;   // masks this block handles
    if (rounds <= 0) return;

    float4 rA[4], rB[4];
    // prologue: mask0 -> LDS via rB; issue mask1 -> rA, mask2 -> rB
    {
        const float* g = mptr(b);
        #pragma unroll
        for (int j = 0; j < 4; ++j) rB[j] = *(const float4*)(g + j * (SBLK * 4) + tid * 4);
        #pragma unroll
        for (int j = 0; j < 4; ++j) *(float4*)&buf[0][j * (SBLK * 4) + tid * 4] = rB[j];
        if (1 < rounds) {
            const float* g1 = mptr(b + NBLK);
            #pragma unroll
            for (int j = 0; j < 4; ++j) rA[j] = *(const float4*)(g1 + j * (SBLK * 4) + tid * 4);
        }
        if (2 < rounds) {
            const float* g2 = mptr(b + 2 * NBLK);
            #pragma unroll
            for (int j = 0; j < 4; ++j) rB[j] = *(const float4*)(g2 + j * (SBLK * 4) + tid * 4);
        }
    }
    LDS_BARRIER();

    // one mask: prep next buffer from reg-set R, refill R from mask k+3, sample buf[k&1]
    #define DO_MASK(kk, R)                                                                 \
    {                                                                                      \
        const int cur = (kk) & 1;                                                          \
        const int mi = b + (kk) * NBLK;                                                    \
        if ((kk) + 1 < rounds) {                                                           \
            _Pragma("unroll")                                                              \
            for (int j = 0; j < 4; ++j)                                                    \
                *(float4*)&buf[cur ^ 1][j * (SBLK * 4) + tid * 4] = R[j];                  \
            if ((kk) + 3 < rounds) {                                                       \
                const float* gn = mptr(b + ((kk) + 3) * NBLK);                             \
                _Pragma("unroll")                                                          \
                for (int j = 0; j < 4; ++j)                                                \
                    R[j] = *(const float4*)(gn + j * (SBLK * 4) + tid * 4);                \
            }                                                                              \
        }                                                                                  \
        const float* lm = &buf[cur][0];                                                    \
        const bool sig = (mi < N);                                                         \
        ushort4_t* o4 = sig ? (ushort4_t*)(S + (size_t)mi * P)                             \
                            : (ushort4_t*)(tsamp + (size_t)(mi - N) * P);                  \
        float sum = 0.f;                                                                   \
        _Pragma("unroll")                                                                  \
        for (int it = 0; it < 4; ++it) {                                                   \
            int q = it * SBLK + tid;                                                       \
            if (q < nq) {                                                                  \
                float v[4];                                                                \
                int bi[4] = {idr[it].x, idr[it].y, idr[it].z, idr[it].w};                   \
                unsigned wa[4] = {war[it].x, war[it].z, wbr[it].x, wbr[it].z};              \
                unsigned wb[4] = {war[it].y, war[it].w, wbr[it].y, wbr[it].w};              \
                _Pragma("unroll")                                                          \
                for (int p2 = 0; p2 < 4; ++p2) {                                           \
                    int bb = bi[p2];                                                       \
                    float t00 = lm[bb], t01 = lm[bb + 1];                                  \
                    float t10 = lm[bb + HW], t11 = lm[bb + HW + 1];                        \
                    float vv = asf(wa[p2] << 16) * t00 + asf(wa[p2] & 0xffff0000u) * t01   \
                             + asf(wb[p2] << 16) * t10 + asf(wb[p2] & 0xffff0000u) * t11;  \
                    if (sig) vv = __builtin_amdgcn_rcpf(1.f + __expf(-vv));                \
                    v[p2] = vv;                                                            \
                }                                                                          \
                ushort4_t o = {f2bf(v[0]), f2bf(v[1]), f2bf(v[2]), f2bf(v[3])};            \
                o4[q] = o;                                                                 \
                sum += (v[0] + v[1]) + (v[2] + v[3]);                                      \
            }                                                                              \
        }                                                                                  \
        _Pragma("unroll")                                                                  \
        for (int m2 = 32; m2 > 0; m2 >>= 1) sum += __shfl_xor(sum, m2, 64);                \
        if ((tid & 63) == 0) wred[(kk) & 1][tid >> 6] = sum;                               \
        LDS_BARRIER();                                                                     \
        if (tid == 0) {                                                                    \
            float s = 0.f;                                                                 \
            _Pragma("unroll")                                                              \
            for (int w2 = 0; w2 < SBLK / 64; ++w2) s += wred[(kk) & 1][w2];                \
            if (sig) ssum[mi] = s;                                                         \
            else tsum[mi - N] = s;                                                         \
        }                                                                                  \
    }

    int k = 0;
    while (true) {
        DO_MASK(k, rA);             // even k: buffer-prep from rA
        ++k;
        if (k >= rounds) break;
        DO_MASK(k, rB);             // odd k: buffer-prep from rB
        ++k;
        if (k >= rounds) break;
    }
    #undef DO_MASK
}

// ---------- kernel 3: MFMA split-K GEMM: Cpart[ks][n][t] = sum_k S[n,k]*Tm[t,k] ----------
#define LDF(Aarr, Barr, kof)                                                              \
    do {                                                                                  \
        _Pragma("unroll") for (int m_ = 0; m_ < 3; ++m_)                                  \
            Aarr[m_] = *(const short8*)(pa + (size_t)m_ * 16 * P + (kof));                \
        _Pragma("unroll") for (int j_ = 0; j_ < 5; ++j_)                                  \
            Barr[j_] = *(const short8*)(pb + (size_t)j_ * 16 * P + (kof));                \
    } while (0)

#define FMAS(Aarr, Barr)                                                                  \
    do {                                                                                  \
        _Pragma("unroll") for (int m_ = 0; m_ < 3; ++m_) {                                \
            _Pragma("unroll") for (int j_ = 0; j_ < 5; ++j_)                              \
                acc[m_][j_] = __builtin_amdgcn_mfma_f32_16x16x32_bf16(                    \
                    Aarr[m_], Barr[j_], acc[m_][j_], 0, 0, 0);                            \
        }                                                                                 \
    } while (0)

__global__ __launch_bounds__(256) void kgemm(const ushort_t* __restrict__ S,
                                             const ushort_t* __restrict__ Tm,
                                             float* __restrict__ Cpart,
                                             const int* __restrict__ lvl,
                                             int N, int T, int P, int nsteps) {
    if (*lvl >= 2) return;
    int tid = threadIdx.x;
    int wid = tid >> 6, lane = tid & 63;
    int wm = wid >> 1, wt = wid & 1;
    int r = lane & 15, g = lane >> 4;
    int n0 = blockIdx.x * 96 + wm * 48;
    int t0 = wt * 80;
    size_t k0 = (size_t)blockIdx.y * nsteps * 32 + g * 8;
    const ushort_t* pa = S + (size_t)(n0 + r) * P + k0;
    const ushort_t* pb = Tm + (size_t)(t0 + r) * P + k0;

    f32x4 acc[3][5];
    #pragma unroll
    for (int m2 = 0; m2 < 3; ++m2)
        #pragma unroll
        for (int j2 = 0; j2 < 5; ++j2) acc[m2][j2] = (f32x4){0.f, 0.f, 0.f, 0.f};

    short8 a0[3], b0[5], a1[3], b1[5];
    LDF(a0, b0, 0);
    int ks = 0;
    for (; ks + 2 < nsteps; ks += 2) {
        LDF(a1, b1, (ks + 1) * 32);
        FMAS(a0, b0);
        LDF(a0, b0, (ks + 2) * 32);
        FMAS(a1, b1);
    }
    LDF(a1, b1, (ks + 1) * 32);
    FMAS(a0, b0);
    FMAS(a1, b1);

    size_t cb = (size_t)blockIdx.y * N * T;
    #pragma unroll
    for (int m2 = 0; m2 < 3; ++m2)
        #pragma unroll
        for (int j2 = 0; j2 < 5; ++j2)
            #pragma unroll
            for (int q = 0; q < 4; ++q) {
                int row = n0 + m2 * 16 + g * 4 + q;
                int col = t0 + j2 * 16 + r;
                Cpart[cb + (size_t)row * T + col] = acc[m2][j2][q];
            }
}

// ---------- kernel 4: epilogue ----------
__global__ void kfinal(const float* __restrict__ logits, const float* __restrict__ opts,
                       const float* __restrict__ tpts, const float* __restrict__ Cpart,
                       const float* __restrict__ ssum, const float* __restrict__ tsum,
                       const int* __restrict__ lvl, float* __restrict__ out,
                       int N, int T, int nks) {
    int idx = blockIdx.x * 256 + threadIdx.x;
    if (idx >= N * T) return;
    int n = idx / T, t = idx - n * T;

    float lg = logits[n];
    float p = 1.f / (1.f + __expf(-lg));
    float pos = 0.25f * (1.f - p) * (1.f - p) * (-logf(p + 1e-8f));
    float neg = 0.75f * p * p * (-logf(1.f - p + 1e-8f));
    float ccls = pos - neg;

    float kp = 0.f;
    const float4* a4 = (const float4*)(opts + (size_t)n * 32);
    const float4* b4 = (const float4*)(tpts + (size_t)t * 32);
    #pragma unroll
    for (int j = 0; j < 8; ++j) {
        float4 a = a4[j], b = b4[j];
        kp += fabsf(a.x - b.x) + fabsf(a.y - b.y) + fabsf(a.z - b.z) + fabsf(a.w - b.w);
    }

    float dice = 0.f;
    if (*lvl < 2) {
        float dot = 0.f;
        for (int ks = 0; ks < nks; ++ks) dot += Cpart[(size_t)ks * N * T + idx];
        dice = 1.f - (2.f * dot + 1.f) / (ssum[n] + tsum[t] + 1.f);
    }
    out[idx] = 2.f * ccls + 5.f * kp + 5.f * dice;
}

extern "C" void kernel_launch(void* const* d_in, const int* in_sizes, int n_in,
                              void* d_out, int out_size, void* d_ws, size_t ws_size,
                              hipStream_t stream) {
    const float* logits = (const float*)d_in[0];
    const float* cpts   = (const float*)d_in[1];
    const float* pmask  = (const float*)d_in[2];
    const float* tpts   = (const float*)d_in[3];
    const float* tmasks = (const float*)d_in[4];
    const float* coords = (const float*)d_in[5];
    const int*   lvl    = (const int*)d_in[6];
    float* out = (float*)d_out;

    int N = in_sizes[0];        // 2400
    int T = in_sizes[3] / 32;   // 160
    int P = in_sizes[5] / 2;    // 12544

    char* w = (char*)d_ws;
    auto alloc = [&](size_t bytes) {
        char* r = w;
        w += (bytes + 255) & ~(size_t)255;
        return r;
    };
    int*      idxb  = (int*)alloc((size_t)P * 4);
    uint2*    wpkb  = (uint2*)alloc((size_t)P * 8);
    ushort_t* tsamp = (ushort_t*)alloc((size_t)T * P * 2);
    ushort_t* S     = (ushort_t*)alloc((size_t)N * P * 2);
    float*    ssumb = (float*)alloc((size_t)N * 4);
    float*    tsumb = (float*)alloc((size_t)T * 4);
    size_t base_bytes = (size_t)(w - (char*)d_ws);

    int nks = 14;               // 25x14 = 350 blocks; Cpart round-trip halved vs 28
    if (base_bytes + (size_t)nks * N * T * 4 > ws_size) nks = 7;
    int nsteps = (P / 32) / nks;
    float* Cpart = (float*)alloc((size_t)nks * N * T * 4);

    kprep<<<(P + 255) / 256, 256, 0, stream>>>(coords, idxb, wpkb, P);
    ksamp_all<<<NBLK, SBLK, 0, stream>>>(pmask, tmasks, idxb, wpkb, S, tsamp,
                                         ssumb, tsumb, lvl, N, T, P);
    kgemm<<<dim3(N / 96, nks), 256, 0, stream>>>(S, tsamp, Cpart, lvl, N, T, P, nsteps);
    kfinal<<<(N * T + 255) / 256, 256, 0, stream>>>(logits, cpts, tpts, Cpart, ssumb, tsumb,
                                                    lvl, out, N, T, nks);
}

// Round 10
// 119.339 us; speedup vs baseline: 1.4939x; 1.4867x over previous
//
#include <hip/hip_runtime.h>
#include <hip/hip_bf16.h>
#include <cstdint>

#define HW 128
#define MASK_ELEMS (HW * HW)
#define SBLK 1024      // sampler block size (16 waves)
#define NBLK 256       // sampler grid size (1 block/CU via 128KB LDS)

typedef unsigned short ushort_t;
typedef __attribute__((ext_vector_type(4))) unsigned short ushort4_t;
typedef __attribute__((ext_vector_type(8))) short short8;
typedef __attribute__((ext_vector_type(4))) float f32x4;

__device__ __forceinline__ float asf(unsigned int u) {
    union { unsigned int i; float f; } c;
    c.i = u;
    return c.f;
}
__device__ __forceinline__ ushort_t f2bf(float f) {
    union { float f; unsigned int i; } c;
    c.f = f;
    unsigned int r = c.i + 0x7FFFu + ((c.i >> 16) & 1u);  // RNE
    return (ushort_t)(r >> 16);
}

// LDS-visibility-only barrier: NO vmcnt drain (keeps stage loads/stores in flight).
#define LDS_BARRIER()                                         \
    do {                                                      \
        asm volatile("s_waitcnt lgkmcnt(0)" ::: "memory");    \
        __builtin_amdgcn_s_barrier();                         \
    } while (0)

// ---------- kernel 1: per-point bilinear setup -> base idx + 4 packed bf16 weight products ----
// Base b clamped so bx<=126, by<=126: taps {b, b+1, b+128, b+129} all in [0,16384).
__global__ void kprep(const float* __restrict__ coords, int* __restrict__ idx,
                      uint2* __restrict__ wpk, int P) {
    int i = blockIdx.x * 256 + threadIdx.x;
    if (i >= P) return;
    float cx = coords[2 * i], cy = coords[2 * i + 1];
    float x = cx * (float)HW - 0.5f;
    float y = cy * (float)HW - 0.5f;
    float x0f = floorf(x), y0f = floorf(y);
    float wx1 = x - x0f, wy1 = y - y0f;
    float wx0 = 1.f - wx1, wy0 = 1.f - wy1;
    int x0 = (int)x0f, y0 = (int)y0f;

    float wxA = (x0 >= 0) ? wx0 : wx1;
    float wxB = (x0 >= 0 && x0 < HW - 1) ? wx1 : 0.f;
    float wyA = (y0 >= 0) ? wy0 : wy1;
    float wyB = (y0 >= 0 && y0 < HW - 1) ? wy1 : 0.f;
    int bx = max(x0, 0), by = max(y0, 0);
    if (bx > HW - 2) { bx = HW - 2; wxB = wxA; wxA = 0.f; }
    if (by > HW - 2) { by = HW - 2; wyB = wyA; wyA = 0.f; }

    idx[i] = by * HW + bx;
    wpk[i] = make_uint2((unsigned)f2bf(wxA * wyA) | ((unsigned)f2bf(wxB * wyA) << 16),
                        (unsigned)f2bf(wxA * wyB) | ((unsigned)f2bf(wxB * wyB) << 16));
}

// ---------- kernel 2: persistent fused sampler, packed-pair bf16 tile, 2-deep pipeline ----
// LDS tile: lmp[i] = (bf16 m[i], bf16 m[i+1]) -> one adjacent-base pair of u32 reads per
// point (ds_read2-mergeable), halving LDS instrs+conflicts vs the 4-dword f32 gather.
// Staging: mask k+1 held in 20 regs while sampling mask k; loads for k+2 issued early.
// amdgpu_waves_per_eu(4,4) pins the VGPR budget at 128 (launch_bounds' min-only semantics
// let the compiler target 8 waves/EU = 64 VGPR and spill 160MB/launch to scratch — r8/r9).
__device__ __forceinline__ void load_mask_regs(const float* __restrict__ g, int tid,
                                               float4 rS[4], float rN[4]) {
    #pragma unroll
    for (int j = 0; j < 4; ++j) {
        int o = j * (SBLK * 4) + tid * 4;
        rS[j] = *(const float4*)(g + o);
        rN[j] = g[min(o + 4, MASK_ELEMS - 1)];
    }
}
__device__ __forceinline__ void pack_to_lds(unsigned* l, int tid, const float4 rS[4],
                                            const float rN[4]) {
    #pragma unroll
    for (int j = 0; j < 4; ++j) {
        int o = j * (SBLK * 4) + tid * 4;
        float4 v = rS[j];
        unsigned bx = (unsigned)f2bf(v.x), by = (unsigned)f2bf(v.y);
        unsigned bz = (unsigned)f2bf(v.z), bw = (unsigned)f2bf(v.w);
        unsigned bn = (unsigned)f2bf(rN[j]);
        uint4 e = make_uint4(bx | (by << 16), by | (bz << 16),
                             bz | (bw << 16), bw | (bn << 16));
        *(uint4*)&l[o] = e;
    }
}

__attribute__((amdgpu_waves_per_eu(4, 4)))
__global__ void __launch_bounds__(SBLK) ksamp_all(
        const float* __restrict__ pmask, const float* __restrict__ tmasks,
        const int* __restrict__ idx, const uint2* __restrict__ wpk,
        ushort_t* __restrict__ S, ushort_t* __restrict__ tsamp,
        float* __restrict__ ssum, float* __restrict__ tsum,
        const int* __restrict__ lvl, int N, int T, int P) {
    if (*lvl >= 2) return;
    __shared__ unsigned buf[2][MASK_ELEMS];  // 2 x 64KB packed-pair tiles
    __shared__ float wred[2][SBLK / 64];
    const int tid = threadIdx.x;
    const int NM = N + T;
    const int nq = P >> 2;

    // ---- mask-invariant point metadata in registers (48 VGPR) ----
    int4 idr[4];
    uint4 war[4], wbr[4];
    #pragma unroll
    for (int it = 0; it < 4; ++it) {
        int q = it * SBLK + tid;
        if (q < nq) {
            idr[it] = ((const int4*)idx)[q];
            war[it] = ((const uint4*)wpk)[2 * q];
            wbr[it] = ((const uint4*)wpk)[2 * q + 1];
        } else {
            idr[it] = make_int4(0, 0, 0, 0);
            war[it] = make_uint4(0, 0, 0, 0);
            wbr[it] = make_uint4(0, 0, 0, 0);
        }
    }

    auto mptr = [&](int mi) -> const float* {
        return (mi < N) ? pmask + (size_t)mi * MASK_ELEMS
                        : tmasks + (size_t)(mi - N) * MASK_ELEMS;
    };

    const int b = blockIdx.x;
    const int rounds = (NM - b + NBLK - 1) / NBLK;
    if (rounds <= 0) return;

    float4 rS[4];
    float rN[4];
    load_mask_regs(mptr(b), tid, rS, rN);
    pack_to_lds(buf[0], tid, rS, rN);
    if (rounds > 1) load_mask_regs(mptr(b + NBLK), tid, rS, rN);
    LDS_BARRIER();

    int cur = 0;
    for (int k = 0; k < rounds; ++k) {
        if (k + 1 < rounds) {
            pack_to_lds(buf[cur ^ 1], tid, rS, rN);          // mask k+1 -> other buffer
            if (k + 2 < rounds)
                load_mask_regs(mptr(b + (k + 2) * NBLK), tid, rS, rN);  // k+2 in flight
        }
        const unsigned* lm = buf[cur];
        const int mi = b + k * NBLK;
        const bool sig = (mi < N);
        ushort4_t* o4 = sig ? (ushort4_t*)(S + (size_t)mi * P)
                            : (ushort4_t*)(tsamp + (size_t)(mi - N) * P);
        float sum = 0.f;
        #pragma unroll
        for (int it = 0; it < 4; ++it) {
            int q = it * SBLK + tid;
            if (q < nq) {
                float v[4];
                int bi[4] = {idr[it].x, idr[it].y, idr[it].z, idr[it].w};
                unsigned wa[4] = {war[it].x, war[it].z, wbr[it].x, wbr[it].z};
                unsigned wb[4] = {war[it].y, war[it].w, wbr[it].y, wbr[it].w};
                #pragma unroll
                for (int p2 = 0; p2 < 4; ++p2) {
                    int bb = bi[p2];
                    unsigned r0 = lm[bb];        // (m[b], m[b+1])
                    unsigned r1 = lm[bb + HW];   // (m[b+128], m[b+129])
                    float vv = asf(wa[p2] << 16) * asf(r0 << 16)
                             + asf(wa[p2] & 0xffff0000u) * asf(r0 & 0xffff0000u)
                             + asf(wb[p2] << 16) * asf(r1 << 16)
                             + asf(wb[p2] & 0xffff0000u) * asf(r1 & 0xffff0000u);
                    if (sig) vv = __builtin_amdgcn_rcpf(1.f + __expf(-vv));
                    v[p2] = vv;
                }
                ushort4_t o = {f2bf(v[0]), f2bf(v[1]), f2bf(v[2]), f2bf(v[3])};
                o4[q] = o;
                sum += (v[0] + v[1]) + (v[2] + v[3]);
            }
        }
        #pragma unroll
        for (int m2 = 32; m2 > 0; m2 >>= 1) sum += __shfl_xor(sum, m2, 64);
        if ((tid & 63) == 0) wred[k & 1][tid >> 6] = sum;
        LDS_BARRIER();
        if (tid == 0) {
            float s = 0.f;
            #pragma unroll
            for (int w2 = 0; w2 < SBLK / 64; ++w2) s += wred[k & 1][w2];
            if (sig) ssum[mi] = s;
            else tsum[mi - N] = s;
        }
        cur ^= 1;
    }
}

// ---------- kernel 3: MFMA split-K GEMM: Cpart[ks][n][t] = sum_k S[n,k]*Tm[t,k] ----------
#define LDF(Aarr, Barr, kof)                                                              \
    do {                                                                                  \
        _Pragma("unroll") for (int m_ = 0; m_ < 3; ++m_)                                  \
            Aarr[m_] = *(const short8*)(pa + (size_t)m_ * 16 * P + (kof));                \
        _Pragma("unroll") for (int j_ = 0; j_ < 5; ++j_)                                  \
            Barr[j_] = *(const short8*)(pb + (size_t)j_ * 16 * P + (kof));                \
    } while (0)

#define FMAS(Aarr, Barr)                                                                  \
    do {                                                                                  \
        _Pragma("unroll") for (int m_ = 0; m_ < 3; ++m_) {                                \
            _Pragma("unroll") for (int j_ = 0; j_ < 5; ++j_)                              \
                acc[m_][j_] = __builtin_amdgcn_mfma_f32_16x16x32_bf16(                    \
                    Aarr[m_], Barr[j_], acc[m_][j_], 0, 0, 0);                            \
        }                                                                                 \
    } while (0)

__global__ __launch_bounds__(256) void kgemm(const ushort_t* __restrict__ S,
                                             const ushort_t* __restrict__ Tm,
                                             float* __restrict__ Cpart,
                                             const int* __restrict__ lvl,
                                             int N, int T, int P, int nsteps) {
    if (*lvl >= 2) return;
    int tid = threadIdx.x;
    int wid = tid >> 6, lane = tid & 63;
    int wm = wid >> 1, wt = wid & 1;
    int r = lane & 15, g = lane >> 4;
    int n0 = blockIdx.x * 96 + wm * 48;
    int t0 = wt * 80;
    size_t k0 = (size_t)blockIdx.y * nsteps * 32 + g * 8;
    const ushort_t* pa = S + (size_t)(n0 + r) * P + k0;
    const ushort_t* pb = Tm + (size_t)(t0 + r) * P + k0;

    f32x4 acc[3][5];
    #pragma unroll
    for (int m2 = 0; m2 < 3; ++m2)
        #pragma unroll
        for (int j2 = 0; j2 < 5; ++j2) acc[m2][j2] = (f32x4){0.f, 0.f, 0.f, 0.f};

    short8 a0[3], b0[5], a1[3], b1[5];
    LDF(a0, b0, 0);
    int ks = 0;
    for (; ks + 2 < nsteps; ks += 2) {
        LDF(a1, b1, (ks + 1) * 32);
        FMAS(a0, b0);
        LDF(a0, b0, (ks + 2) * 32);
        FMAS(a1, b1);
    }
    LDF(a1, b1, (ks + 1) * 32);
    FMAS(a0, b0);
    FMAS(a1, b1);

    size_t cb = (size_t)blockIdx.y * N * T;
    #pragma unroll
    for (int m2 = 0; m2 < 3; ++m2)
        #pragma unroll
        for (int j2 = 0; j2 < 5; ++j2)
            #pragma unroll
            for (int q = 0; q < 4; ++q) {
                int row = n0 + m2 * 16 + g * 4 + q;
                int col = t0 + j2 * 16 + r;
                Cpart[cb + (size_t)row * T + col] = acc[m2][j2][q];
            }
}

// ---------- kernel 4: epilogue ----------
__global__ void kfinal(const float* __restrict__ logits, const float* __restrict__ opts,
                       const float* __restrict__ tpts, const float* __restrict__ Cpart,
                       const float* __restrict__ ssum, const float* __restrict__ tsum,
                       const int* __restrict__ lvl, float* __restrict__ out,
                       int N, int T, int nks) {
    int idx = blockIdx.x * 256 + threadIdx.x;
    if (idx >= N * T) return;
    int n = idx / T, t = idx - n * T;

    float lg = logits[n];
    float p = 1.f / (1.f + __expf(-lg));
    float pos = 0.25f * (1.f - p) * (1.f - p) * (-logf(p + 1e-8f));
    float neg = 0.75f * p * p * (-logf(1.f - p + 1e-8f));
    float ccls = pos - neg;

    float kp = 0.f;
    const float4* a4 = (const float4*)(opts + (size_t)n * 32);
    const float4* b4 = (const float4*)(tpts + (size_t)t * 32);
    #pragma unroll
    for (int j = 0; j < 8; ++j) {
        float4 a = a4[j], b = b4[j];
        kp += fabsf(a.x - b.x) + fabsf(a.y - b.y) + fabsf(a.z - b.z) + fabsf(a.w - b.w);
    }

    float dice = 0.f;
    if (*lvl < 2) {
        float dot = 0.f;
        for (int ks = 0; ks < nks; ++ks) dot += Cpart[(size_t)ks * N * T + idx];
        dice = 1.f - (2.f * dot + 1.f) / (ssum[n] + tsum[t] + 1.f);
    }
    out[idx] = 2.f * ccls + 5.f * kp + 5.f * dice;
}

extern "C" void kernel_launch(void* const* d_in, const int* in_sizes, int n_in,
                              void* d_out, int out_size, void* d_ws, size_t ws_size,
                              hipStream_t stream) {
    const float* logits = (const float*)d_in[0];
    const float* cpts   = (const float*)d_in[1];
    const float* pmask  = (const float*)d_in[2];
    const float* tpts   = (const float*)d_in[3];
    const float* tmasks = (const float*)d_in[4];
    const float* coords = (const float*)d_in[5];
    const int*   lvl    = (const int*)d_in[6];
    float* out = (float*)d_out;

    int N = in_sizes[0];        // 2400
    int T = in_sizes[3] / 32;   // 160
    int P = in_sizes[5] / 2;    // 12544

    char* w = (char*)d_ws;
    auto alloc = [&](size_t bytes) {
        char* r = w;
        w += (bytes + 255) & ~(size_t)255;
        return r;
    };
    int*      idxb  = (int*)alloc((size_t)P * 4);
    uint2*    wpkb  = (uint2*)alloc((size_t)P * 8);
    ushort_t* tsamp = (ushort_t*)alloc((size_t)T * P * 2);
    ushort_t* S     = (ushort_t*)alloc((size_t)N * P * 2);
    float*    ssumb = (float*)alloc((size_t)N * 4);
    float*    tsumb = (float*)alloc((size_t)T * 4);
    size_t base_bytes = (size_t)(w - (char*)d_ws);

    int nks = 14;
    if (base_bytes + (size_t)nks * N * T * 4 > ws_size) nks = 7;
    int nsteps = (P / 32) / nks;
    float* Cpart = (float*)alloc((size_t)nks * N * T * 4);

    kprep<<<(P + 255) / 256, 256, 0, stream>>>(coords, idxb, wpkb, P);
    ksamp_all<<<NBLK, SBLK, 0, stream>>>(pmask, tmasks, idxb, wpkb, S, tsamp,
                                         ssumb, tsumb, lvl, N, T, P);
    kgemm<<<dim3(N / 96, nks), 256, 0, stream>>>(S, tsamp, Cpart, lvl, N, T, P, nsteps);
    kfinal<<<(N * T + 255) / 256, 256, 0, stream>>>(logits, cpts, tpts, Cpart, ssumb, tsumb,
                                                    lvl, out, N, T, nks);
}